// Round 4
// baseline (397.282 us; speedup 1.0000x reference)
//
#include <hip/hip_runtime.h>

#define BB 4096
#define SS 128
#define NB 16
#define NT 256

typedef __attribute__((ext_vector_type(8))) short short8;
typedef __attribute__((ext_vector_type(4))) float f32x4;
typedef unsigned short ushort_t;
typedef unsigned int uint_t;

#define SX_STR   72
#define SH1_STR  264
#define SEMB_STR 136
#define SH_STR   72
#define ENC_LDS_USHORTS (32 * SH1_STR + 32 * SEMB_STR)   // 12800 -> 25.6 KB

__device__ __forceinline__ ushort_t f2bf(float f) {
    union { float f; unsigned u; } x; x.f = f;
    unsigned r = x.u + 0x7FFFu + ((x.u >> 16) & 1u);
    return (ushort_t)(r >> 16);
}
__device__ __forceinline__ uint_t pack2(float a, float b) {
    return (uint_t)f2bf(a) | ((uint_t)f2bf(b) << 16);
}
__device__ __forceinline__ float bflo(uint_t u) {
    union { unsigned u; float f; } x; x.u = u << 16; return x.f;
}
__device__ __forceinline__ float bfhi(uint_t u) {
    union { unsigned u; float f; } x; x.u = u & 0xFFFF0000u; return x.f;
}
__device__ __forceinline__ float bf2f(ushort_t h) {
    union { unsigned u; float f; } x; x.u = ((unsigned)h) << 16; return x.f;
}
__device__ __forceinline__ float fsig(float x) {
    return __builtin_amdgcn_rcpf(1.f + __expf(-x));
}
__device__ __forceinline__ float ftanh(float x) {
    return 1.f - 2.f * __builtin_amdgcn_rcpf(__expf(2.f * x) + 1.f);
}
// workgroup barrier WITHOUT vmcnt drain (LDS ordering only)
__device__ __forceinline__ void barrier_lgkm() {
    asm volatile("s_waitcnt lgkmcnt(0)\n\ts_barrier" ::: "memory");
}

union FragU { short8 v; ushort_t u[8]; };

// ============================================================================
// Prep: bf16 B-fragment images for W1/W2/Wih/Whh.
// ============================================================================
__global__ void podcritic_prep(const float* __restrict__ W1, const float* __restrict__ W2,
                               const float* __restrict__ Wih, const float* __restrict__ Whh,
                               short8* __restrict__ img)
{
    const int W = blockIdx.x * 4 + (threadIdx.x >> 6);   // 0..191
    const int l = threadIdx.x & 63;
    const int q = l >> 4, m = l & 15;
    FragU u;
    #pragma unroll
    for (int j = 0; j < 8; ++j) {
        float v;
        if (W < 32)       { int nt = W >> 1,        kk = W & 1;        int k = kk*32 + q*8 + j;
                            v = (k < 47) ? W1[k*256 + nt*16 + m] : 0.f; }
        else if (W < 96)  { int f = W - 32, nt = f >> 3, kk = f & 7;   int k = kk*32 + q*8 + j;
                            v = W2[k*128 + nt*16 + m]; }
        else if (W < 160) { int f = W - 96, nt = f >> 2, kk = f & 3;   int k = kk*32 + q*8 + j;
                            v = Wih[k*256 + nt*16 + m]; }
        else              { int f = W - 160, nt = f >> 1, kk = f & 1;  int k = kk*32 + q*8 + j;
                            v = Whh[k*256 + nt*16 + m]; }
        u.u[j] = f2bf(v);
    }
    img[W * 64 + l] = u.v;
}

// ============================================================================
// Encoder block: M=32 rows (2 steps x 16 batch), 3 lgkm barriers.
// Branchless gather; biases folded into accumulator init; per-phase
// fragment loads (compiler sinks them; keeps VGPR ~52).
// Works for any even chunk length cs: nenc = 128*cs blocks, ytile = e>>8.
// ============================================================================
__device__ __forceinline__ void enc_block(
    ushort_t* smem,
    const float* __restrict__ self_obs, const float* __restrict__ tm_obs,
    const float* __restrict__ en_obs,   const float* __restrict__ cp_obs,
    const float* __restrict__ b1, const float* __restrict__ b2,
    const float* __restrict__ bih, const float* __restrict__ bhh,
    const short8* __restrict__ img, uint_t* __restrict__ wx, int c0, int e)
{
    ushort_t* sh1 = smem;                     // 32*SH1_STR
    ushort_t* sxe = smem + 32 * SH1_STR;      // 32*SEMB_STR (x then emb)

    const int t = threadIdx.x;
    const int w = t >> 6, l = t & 63, q = l >> 4, m = l & 15;
    const int bg = e & 255, b0 = bg * NB;
    const int ytile = e >> 8;
    const int sbase = c0 + ytile * 2;

    // ---- branchless gather: resolve (ptr,stride,scale) once per lane ----
    {
        const int col = t & 63, rw0 = t >> 6;
        const float* p; int stride, soff; float scale;
        if (col < 15)      { p = self_obs + col;      stride = 15; soff = 0;  scale = 0.5f; }
        else if (col < 28) { p = tm_obs + (col - 15); stride = 13; soff = 0;  scale = 0.5f; }
        else if (col < 41) { p = en_obs + (col - 28); stride = 26; soff = 13; scale = 0.5f; }
        else if (col < 47) { p = cp_obs + (col - 41); stride = 6;  soff = 0;  scale = 0.5f; }
        else               { p = self_obs;            stride = 0;  soff = 0;  scale = 0.f; }
        #pragma unroll
        for (int jj = 0; jj < 8; ++jj) {
            int rr = 4 * jj + rw0;
            int mt = rr >> 4, r = rr & 15;
            int bs = (b0 + r) * SS + sbase + mt;
            int o = bs * stride;
            float v = scale * (p[o] + p[o + soff]);
            sxe[rr * SX_STR + col] = f2bf(v);
        }
    }
    float bias1[4], bias2[2], bgf[4];
    #pragma unroll
    for (int i = 0; i < 4; ++i) bias1[i] = b1[w * 64 + i * 16 + m];
    #pragma unroll
    for (int i = 0; i < 2; ++i) bias2[i] = b2[32 * w + 16 * i + m];
    #pragma unroll
    for (int i = 0; i < 4; ++i) { int n = (w + 4 * i) * 16 + m; bgf[i] = bih[n] + bhh[n]; }
    barrier_lgkm();

    // ---- phase 1: H1 = relu(x @ W1 + b1), M=32; bias in acc init ----
    {
        short8 w1f[4][2];
        #pragma unroll
        for (int i = 0; i < 4; ++i)
            #pragma unroll
            for (int kk = 0; kk < 2; ++kk)
                w1f[i][kk] = img[(((4 * w + i) * 2) + kk) * 64 + l];
        f32x4 c1[2][4];
        #pragma unroll
        for (int mt = 0; mt < 2; ++mt)
            #pragma unroll
            for (int i = 0; i < 4; ++i)
                c1[mt][i] = (f32x4){bias1[i], bias1[i], bias1[i], bias1[i]};
        #pragma unroll
        for (int kk = 0; kk < 2; ++kk) {
            #pragma unroll
            for (int mt = 0; mt < 2; ++mt) {
                short8 a = *(const short8*)&sxe[(mt * 16 + m) * SX_STR + kk * 32 + q * 8];
                #pragma unroll
                for (int i = 0; i < 4; ++i)
                    c1[mt][i] = __builtin_amdgcn_mfma_f32_16x16x32_bf16(a, w1f[i][kk], c1[mt][i], 0, 0, 0);
            }
        }
        #pragma unroll
        for (int mt = 0; mt < 2; ++mt)
            #pragma unroll
            for (int i = 0; i < 4; ++i) {
                int col = w * 64 + i * 16 + m;
                #pragma unroll
                for (int r = 0; r < 4; ++r)
                    sh1[(mt * 16 + q * 4 + r) * SH1_STR + col] = f2bf(fmaxf(c1[mt][i][r], 0.f));
            }
    }
    barrier_lgkm();

    // ---- phase 2: EMB = relu(H1 @ W2 + b2); bias in acc init ----
    {
        short8 w2f[2][8];
        #pragma unroll
        for (int i = 0; i < 2; ++i)
            #pragma unroll
            for (int kk = 0; kk < 8; ++kk)
                w2f[i][kk] = img[(32 + ((2 * w + i) * 8) + kk) * 64 + l];
        f32x4 c2[2][2];
        #pragma unroll
        for (int mt = 0; mt < 2; ++mt)
            #pragma unroll
            for (int i = 0; i < 2; ++i)
                c2[mt][i] = (f32x4){bias2[i], bias2[i], bias2[i], bias2[i]};
        #pragma unroll
        for (int kk = 0; kk < 8; ++kk) {
            #pragma unroll
            for (int mt = 0; mt < 2; ++mt) {
                short8 a = *(const short8*)&sh1[(mt * 16 + m) * SH1_STR + kk * 32 + q * 8];
                #pragma unroll
                for (int i = 0; i < 2; ++i)
                    c2[mt][i] = __builtin_amdgcn_mfma_f32_16x16x32_bf16(a, w2f[i][kk], c2[mt][i], 0, 0, 0);
            }
        }
        #pragma unroll
        for (int mt = 0; mt < 2; ++mt)
            #pragma unroll
            for (int i = 0; i < 2; ++i) {
                int col = 32 * w + 16 * i + m;
                #pragma unroll
                for (int r = 0; r < 4; ++r)
                    sxe[(mt * 16 + q * 4 + r) * SEMB_STR + col] = f2bf(fmaxf(c2[mt][i][r], 0.f));
            }
    }
    barrier_lgkm();

    // ---- phase 3: wx = emb @ Wih + (bih+bhh), swizzled store ----
    {
        short8 wihf[4][4];
        #pragma unroll
        for (int i = 0; i < 4; ++i)
            #pragma unroll
            for (int kk = 0; kk < 4; ++kk)
                wihf[i][kk] = img[(96 + ((w + 4 * i) * 4) + kk) * 64 + l];
        #pragma unroll
        for (int mt = 0; mt < 2; ++mt) {
            f32x4 g[4];
            #pragma unroll
            for (int i = 0; i < 4; ++i) g[i] = (f32x4){bgf[i], bgf[i], bgf[i], bgf[i]};
            #pragma unroll
            for (int kk = 0; kk < 4; ++kk) {
                short8 a = *(const short8*)&sxe[(mt * 16 + m) * SEMB_STR + kk * 32 + q * 8];
                #pragma unroll
                for (int i = 0; i < 4; ++i)
                    g[i] = __builtin_amdgcn_mfma_f32_16x16x32_bf16(a, wihf[i][kk], g[i], 0, 0, 0);
            }
            int slc = ytile * 2 + mt;
            uint_t* dst = wx + (size_t)(slc * 256 + bg) * 2048 + l * 2;
            #pragma unroll
            for (int i = 0; i < 4; ++i) {
                uint2 vv;
                vv.x = pack2(g[i][0], g[i][1]);
                vv.y = pack2(g[i][2], g[i][3]);
                *(uint2*)(dst + (w + 4 * i) * 128) = vv;
            }
        }
    }
}

// ============================================================================
// Recurrence block with FUSED value head (paired every 2 steps):
// 4 waves / 16 batch rows, 1 lgkm barrier/step, 2-deep wx prefetch.
// After each ODD step both h buffers hold valid h (h(sl) in the buffer being
// read, h(sl+1) in the buffer just written). h(sl) is read EARLY during the
// odd step (that buffer is only overwritten at step sl+2, after another
// barrier); h(sl+1) after the odd step's barrier. Two independent 16-lane
// reduction trees run with ILP; one float2 store per row per 2 steps.
// ============================================================================
__device__ __forceinline__ void rec_block(
    ushort_t* smem,
    const short8* __restrict__ whhimg, const uint_t* __restrict__ wx,
    ushort_t* __restrict__ hws, float* __restrict__ cws,
    const float* __restrict__ Wv, const float* __restrict__ bv,
    float* __restrict__ out, int rc0, int first, int last, int csr)
{
    const int t = threadIdx.x;
    const int w = t >> 6, l = t & 63, q = l >> 4, m = l & 15;
    const int bg = blockIdx.x, b0 = bg * NB;
    const int vr = t >> 4, vp = t & 15;           // value-head row / col-group

    short8 whhf[4][2];
    #pragma unroll
    for (int a = 0; a < 4; ++a)
        #pragma unroll
        for (int kk = 0; kk < 2; ++kk)
            whhf[a][kk] = whhimg[(((w + 4 * a) * 2) + kk) * 64 + l];

    const float4 wv = *(const float4*)(Wv + vp * 4);
    const float bvv = bv[0];

    float creg[4], hlast[4] = {0.f, 0.f, 0.f, 0.f};
    if (first) {
        #pragma unroll
        for (int r = 0; r < 4; ++r) creg[r] = 0.f;
        int idx4 = t * 4, row = idx4 >> 6, col = idx4 & 63;
        uint2 z; z.x = 0u; z.y = 0u;
        *(uint2*)&smem[row * SH_STR + col] = z;
    } else {
        int idx4 = t * 4, row = idx4 >> 6, col = idx4 & 63;
        uint2 hv2 = *(const uint2*)((const uint_t*)(hws + (size_t)bg * 1024 + idx4));
        *(uint2*)&smem[row * SH_STR + col] = hv2;
        float4 cv = *(const float4*)(cws + ((size_t)bg * 256 + t) * 4);
        creg[0] = cv.x; creg[1] = cv.y; creg[2] = cv.z; creg[3] = cv.w;
    }

    uint2 upf[2][4];
    {
        const uint_t* p0 = wx + (size_t)(0 * 256 + bg) * 2048 + l * 2;
        const uint_t* p1 = wx + (size_t)(1 * 256 + bg) * 2048 + l * 2;
        #pragma unroll
        for (int a = 0; a < 4; ++a) {
            upf[0][a] = *(const uint2*)(p0 + (w + 4 * a) * 128);
            upf[1][a] = *(const uint2*)(p1 + (w + 4 * a) * 128);
        }
    }

    barrier_lgkm();

    // core of one step (PAR = buffer parity, SLV = step index); no val head.
    #define REC_CORE(PAR, SLV)                                                          \
        const int sl_ = (SLV);                                                          \
        ushort_t* shc = smem + (PAR) * (NB * SH_STR);                                   \
        ushort_t* shn = smem + (1 - (PAR)) * (NB * SH_STR);                             \
        short8 af0 = *(const short8*)&shc[m * SH_STR + q * 8];                          \
        short8 af1 = *(const short8*)&shc[m * SH_STR + 32 + q * 8];                     \
        f32x4 g[4];                                                                     \
        _Pragma("unroll")                                                               \
        for (int a = 0; a < 4; ++a) {                                                   \
            g[a][0] = bflo(upf[PAR][a].x); g[a][1] = bfhi(upf[PAR][a].x);               \
            g[a][2] = bflo(upf[PAR][a].y); g[a][3] = bfhi(upf[PAR][a].y);               \
        }                                                                               \
        {                                                                               \
            int snext = (sl_ + 2 < csr) ? (sl_ + 2) : sl_;                              \
            const uint_t* pn = wx + (size_t)(snext * 256 + bg) * 2048 + l * 2;          \
            _Pragma("unroll")                                                           \
            for (int a = 0; a < 4; ++a)                                                 \
                upf[PAR][a] = *(const uint2*)(pn + (w + 4 * a) * 128);                  \
        }                                                                               \
        _Pragma("unroll")                                                               \
        for (int a = 0; a < 4; ++a) {                                                   \
            g[a] = __builtin_amdgcn_mfma_f32_16x16x32_bf16(af0, whhf[a][0], g[a], 0, 0, 0); \
            g[a] = __builtin_amdgcn_mfma_f32_16x16x32_bf16(af1, whhf[a][1], g[a], 0, 0, 0); \
        }                                                                               \
        _Pragma("unroll")                                                               \
        for (int r = 0; r < 4; ++r) {                                                   \
            float gi = fsig(g[0][r]);                                                   \
            float gf = fsig(g[1][r]);                                                   \
            float gg = ftanh(g[2][r]);                                                  \
            float go = fsig(g[3][r]);                                                   \
            float c  = gf * creg[r] + gi * gg;                                          \
            creg[r] = c;                                                                \
            float h = go * ftanh(c);                                                    \
            hlast[r] = h;                                                               \
            shn[(q * 4 + r) * SH_STR + 16 * w + m] = f2bf(h);                           \
        }

    for (int sl = 0; sl < csr; sl += 2) {
        {   // even step (PAR=0): compute only
            REC_CORE(0, sl);
            barrier_lgkm();
        }
        {   // odd step (PAR=1): compute + dual val head for steps sl, sl+1
            // early read of h(sl) from shc (stable until step sl+2's writes,
            // which happen after the next barrier)
            uint2 hvA = *(const uint2*)&smem[1 * (NB * SH_STR) + vr * SH_STR + vp * 4];
            REC_CORE(1, sl + 1);
            barrier_lgkm();
            uint2 hvB = *(const uint2*)&shn[vr * SH_STR + vp * 4];   // h(sl+1)
            float pvA = bflo(hvA.x) * wv.x + bfhi(hvA.x) * wv.y
                      + bflo(hvA.y) * wv.z + bfhi(hvA.y) * wv.w;
            float pvB = bflo(hvB.x) * wv.x + bfhi(hvB.x) * wv.y
                      + bflo(hvB.y) * wv.z + bfhi(hvB.y) * wv.w;
            pvA += __shfl_xor(pvA, 1, 16);  pvB += __shfl_xor(pvB, 1, 16);
            pvA += __shfl_xor(pvA, 2, 16);  pvB += __shfl_xor(pvB, 2, 16);
            pvA += __shfl_xor(pvA, 4, 16);  pvB += __shfl_xor(pvB, 4, 16);
            pvA += __shfl_xor(pvA, 8, 16);  pvB += __shfl_xor(pvB, 8, 16);
            if (vp == 0) {
                float2 o; o.x = pvA + bvv; o.y = pvB + bvv;
                *(float2*)&out[(size_t)(b0 + vr) * SS + rc0 + sl_ - 1] = o;
            }
        }
    }
    #undef REC_CORE

    if (!last) {
        const int jcol = 16 * w + m;
        #pragma unroll
        for (int r = 0; r < 4; ++r)
            hws[(size_t)bg * 1024 + (q * 4 + r) * 64 + jcol] = f2bf(hlast[r]);
        float4 cv; cv.x = creg[0]; cv.y = creg[1]; cv.z = creg[2]; cv.w = creg[3];
        *(float4*)(cws + ((size_t)bg * 256 + t) * 4) = cv;
    } else {
        const int jcol = 16 * w + m;
        #pragma unroll
        for (int r = 0; r < 4; ++r) {
            int row = b0 + q * 4 + r;
            out[BB * SS + (size_t)row * 64 + jcol]           = hlast[r];
            out[BB * SS + BB * 64 + (size_t)row * 64 + jcol] = creg[r];
        }
    }
}

// ============================================================================
// Combined pipeline dispatch: [0,nrec) rec(chunk i)+fused-val | rest enc(i+1).
// No intra-dispatch dependencies (wx double-buffered).
// ============================================================================
__global__ __launch_bounds__(NT, 4)
void podcritic_step(const float* __restrict__ self_obs, const float* __restrict__ tm_obs,
                    const float* __restrict__ en_obs,   const float* __restrict__ cp_obs,
                    const float* __restrict__ b1, const float* __restrict__ b2,
                    const float* __restrict__ bih, const float* __restrict__ bhh,
                    const short8* __restrict__ img,
                    uint_t* __restrict__ wx_enc, const uint_t* __restrict__ wx_rec,
                    ushort_t* __restrict__ hws, float* __restrict__ cws,
                    const float* __restrict__ Wv, const float* __restrict__ bv,
                    float* __restrict__ out,
                    int enc_c0, int rec_c0, int nrec, int first, int last, int rec_cs)
{
    __shared__ __align__(16) ushort_t smem[ENC_LDS_USHORTS];
    const int bid = blockIdx.x;
    if (bid < nrec) {
        rec_block(smem, img + 160 * 64, wx_rec, hws, cws, Wv, bv, out,
                  rec_c0, first, last, rec_cs);
    } else {
        enc_block(smem, self_obs, tm_obs, en_obs, cp_obs, b1, b2, bih, bhh,
                  img, wx_enc, enc_c0, bid - nrec);
    }
}

// ============================================================================
// Fallback: fused kernel (only if ws too small) — round-2 structure.
// ============================================================================
__global__ __launch_bounds__(NT, 1)
void podcritic_mfma(const float* __restrict__ self_obs,
                    const float* __restrict__ tm_obs,
                    const float* __restrict__ en_obs,
                    const float* __restrict__ cp_obs,
                    const float* __restrict__ W1, const float* __restrict__ b1,
                    const float* __restrict__ W2, const float* __restrict__ b2,
                    const float* __restrict__ Wih, const float* __restrict__ bih,
                    const float* __restrict__ Whh, const float* __restrict__ bhh,
                    const float* __restrict__ Wv, const float* __restrict__ bv,
                    float* __restrict__ out)
{
    __shared__ __align__(16) ushort_t sx[2][NB * SX_STR];
    __shared__ __align__(16) ushort_t sh1[NB * SH1_STR];
    __shared__ __align__(16) ushort_t semb[NB * SEMB_STR];
    __shared__ __align__(16) ushort_t sh[NB * SH_STR];
    __shared__ float sWv[64];

    const int t  = threadIdx.x;
    const int w  = t >> 6;
    const int l  = t & 63;
    const int q  = l >> 4;
    const int m  = l & 15;
    const int b0 = blockIdx.x * NB;

    short8 w1f[4][2];
    short8 w2f[2][8];
    short8 wihf[4][4];
    short8 whhf[4][2];
    float bias1[4], bias2[2], bg[4];

    #pragma unroll
    for (int i = 0; i < 4; ++i) {
        int n = w * 64 + i * 16 + m;
        bias1[i] = b1[n];
        #pragma unroll
        for (int kk = 0; kk < 2; ++kk) {
            FragU u;
            #pragma unroll
            for (int j = 0; j < 8; ++j) {
                int k = kk * 32 + q * 8 + j;
                u.u[j] = f2bf(k < 47 ? W1[k * 256 + n] : 0.f);
            }
            w1f[i][kk] = u.v;
        }
    }
    #pragma unroll
    for (int i = 0; i < 2; ++i) {
        int n = 32 * w + i * 16 + m;
        bias2[i] = b2[n];
        #pragma unroll
        for (int kk = 0; kk < 8; ++kk) {
            FragU u;
            #pragma unroll
            for (int j = 0; j < 8; ++j) {
                int k = kk * 32 + q * 8 + j;
                u.u[j] = f2bf(W2[k * 128 + n]);
            }
            w2f[i][kk] = u.v;
        }
    }
    #pragma unroll
    for (int i = 0; i < 4; ++i) {
        int n = (w + 4 * i) * 16 + m;
        bg[i] = bih[n] + bhh[n];
        #pragma unroll
        for (int kk = 0; kk < 4; ++kk) {
            FragU u;
            #pragma unroll
            for (int j = 0; j < 8; ++j) {
                int k = kk * 32 + q * 8 + j;
                u.u[j] = f2bf(Wih[k * 256 + n]);
            }
            wihf[i][kk] = u.v;
        }
        #pragma unroll
        for (int kk = 0; kk < 2; ++kk) {
            FragU u;
            #pragma unroll
            for (int j = 0; j < 8; ++j) {
                int k = kk * 32 + q * 8 + j;
                u.u[j] = f2bf(Whh[k * 256 + n]);
            }
            whhf[i][kk] = u.v;
        }
    }
    const float bvv = bv[0];
    if (t < 64) sWv[t] = Wv[t];

    for (int idx = t; idx < NB * SH_STR; idx += NT) sh[idx] = 0;

    const int pcol = t & 63;
    const int prow = t >> 6;
    #pragma unroll
    for (int j = 0; j < 4; ++j) {
        int r  = 4 * j + prow;
        int bs = (b0 + r) * SS + 0;
        float v = 0.f;
        if (pcol < 15)      v = self_obs[bs * 15 + pcol];
        else if (pcol < 28) v = tm_obs[bs * 13 + (pcol - 15)];
        else if (pcol < 41) { int kk = pcol - 28;
                              v = 0.5f * (en_obs[(bs * 2) * 13 + kk] + en_obs[(bs * 2) * 13 + 13 + kk]); }
        else if (pcol < 47) v = cp_obs[bs * 6 + (pcol - 41)];
        sx[0][r * SX_STR + pcol] = f2bf(v);
    }
    __syncthreads();

    float creg[4] = {0.f, 0.f, 0.f, 0.f};
    float hreg[4] = {0.f, 0.f, 0.f, 0.f};
    int cur = 0;

    for (int s = 0; s < SS; ++s) {
        float pf[4];
        #pragma unroll
        for (int j = 0; j < 4; ++j) {
            float v = 0.f;
            if (s + 1 < SS) {
                int r  = 4 * j + prow;
                int bs = (b0 + r) * SS + (s + 1);
                if (pcol < 15)      v = self_obs[bs * 15 + pcol];
                else if (pcol < 28) v = tm_obs[bs * 13 + (pcol - 15)];
                else if (pcol < 41) { int kk = pcol - 28;
                                      v = 0.5f * (en_obs[(bs * 2) * 13 + kk] + en_obs[(bs * 2) * 13 + 13 + kk]); }
                else if (pcol < 47) v = cp_obs[bs * 6 + (pcol - 41)];
            }
            pf[j] = v;
        }

        {
            f32x4 c1[4] = {{0,0,0,0},{0,0,0,0},{0,0,0,0},{0,0,0,0}};
            #pragma unroll
            for (int kk = 0; kk < 2; ++kk) {
                short8 a = *(const short8*)&sx[cur][m * SX_STR + kk * 32 + q * 8];
                #pragma unroll
                for (int i = 0; i < 4; ++i)
                    c1[i] = __builtin_amdgcn_mfma_f32_16x16x32_bf16(a, w1f[i][kk], c1[i], 0, 0, 0);
            }
            #pragma unroll
            for (int i = 0; i < 4; ++i) {
                int col = w * 64 + i * 16 + m;
                #pragma unroll
                for (int r = 0; r < 4; ++r)
                    sh1[(q * 4 + r) * SH1_STR + col] = f2bf(fmaxf(c1[i][r] + bias1[i], 0.f));
            }
        }
        __syncthreads();

        {
            f32x4 c2[2] = {{0,0,0,0},{0,0,0,0}};
            #pragma unroll
            for (int kk = 0; kk < 8; ++kk) {
                short8 a = *(const short8*)&sh1[m * SH1_STR + kk * 32 + q * 8];
                #pragma unroll
                for (int i = 0; i < 2; ++i)
                    c2[i] = __builtin_amdgcn_mfma_f32_16x16x32_bf16(a, w2f[i][kk], c2[i], 0, 0, 0);
            }
            #pragma unroll
            for (int i = 0; i < 2; ++i) {
                int col = 32 * w + i * 16 + m;
                #pragma unroll
                for (int r = 0; r < 4; ++r)
                    semb[(q * 4 + r) * SEMB_STR + col] = f2bf(fmaxf(c2[i][r] + bias2[i], 0.f));
            }
        }
        __syncthreads();

        {
            f32x4 g[4];
            #pragma unroll
            for (int i = 0; i < 4; ++i) g[i] = (f32x4){bg[i], bg[i], bg[i], bg[i]};
            #pragma unroll
            for (int kk = 0; kk < 4; ++kk) {
                short8 a = *(const short8*)&semb[m * SEMB_STR + kk * 32 + q * 8];
                #pragma unroll
                for (int i = 0; i < 4; ++i)
                    g[i] = __builtin_amdgcn_mfma_f32_16x16x32_bf16(a, wihf[i][kk], g[i], 0, 0, 0);
            }
            #pragma unroll
            for (int kk = 0; kk < 2; ++kk) {
                short8 a = *(const short8*)&sh[m * SH_STR + kk * 32 + q * 8];
                #pragma unroll
                for (int i = 0; i < 4; ++i)
                    g[i] = __builtin_amdgcn_mfma_f32_16x16x32_bf16(a, whhf[i][kk], g[i], 0, 0, 0);
            }
            const int jcol = 16 * w + m;
            #pragma unroll
            for (int r = 0; r < 4; ++r) {
                float gi = fsig(g[0][r]);
                float gf = fsig(g[1][r]);
                float gg = ftanh(g[2][r]);
                float go = fsig(g[3][r]);
                float c  = gf * creg[r] + gi * gg;
                creg[r] = c;
                float h = go * ftanh(c);
                hreg[r] = h;
                sh[(q * 4 + r) * SH_STR + jcol] = f2bf(h);
            }
            #pragma unroll
            for (int j = 0; j < 4; ++j) {
                int r = 4 * j + prow;
                sx[cur ^ 1][r * SX_STR + pcol] = f2bf(pf[j]);
            }
        }
        __syncthreads();

        {
            int r = t >> 4, pp = t & 15;
            const ushort_t* hp = &sh[r * SH_STR + pp * 4];
            float pv = 0.f;
            #pragma unroll
            for (int j = 0; j < 4; ++j) pv += bf2f(hp[j]) * sWv[pp * 4 + j];
            pv += __shfl_xor(pv, 1, 16);
            pv += __shfl_xor(pv, 2, 16);
            pv += __shfl_xor(pv, 4, 16);
            pv += __shfl_xor(pv, 8, 16);
            if (pp == 0) out[(b0 + r) * SS + s] = pv + bvv;
        }
        cur ^= 1;
    }

    {
        const int jcol = 16 * w + m;
        #pragma unroll
        for (int r = 0; r < 4; ++r) {
            int row = b0 + q * 4 + r;
            out[BB * SS + row * 64 + jcol]           = hreg[r];
            out[BB * SS + BB * 64 + row * 64 + jcol] = creg[r];
        }
    }
}

extern "C" void kernel_launch(void* const* d_in, const int* in_sizes, int n_in,
                              void* d_out, int out_size, void* d_ws, size_t ws_size,
                              hipStream_t stream) {
    const float* self_obs = (const float*)d_in[0];
    const float* tm_obs   = (const float*)d_in[1];
    const float* en_obs   = (const float*)d_in[2];
    const float* cp_obs   = (const float*)d_in[3];
    const float* W1  = (const float*)d_in[4];
    const float* b1  = (const float*)d_in[5];
    const float* W2  = (const float*)d_in[6];
    const float* b2  = (const float*)d_in[7];
    const float* Wih = (const float*)d_in[8];
    const float* bih = (const float*)d_in[9];
    const float* Whh = (const float*)d_in[10];
    const float* bhh = (const float*)d_in[11];
    const float* Wv  = (const float*)d_in[12];
    const float* bv  = (const float*)d_in[13];
    float* out = (float*)d_out;

    const size_t h_bytes   = 256 * 1024 * 2;                // 524,288
    const size_t c_bytes   = 256 * 1024 * 4;                // 1,048,576
    const size_t img_bytes = 192 * 64 * 16;                 // 196,608

    auto need_for = [&](int cs) -> size_t {
        size_t wx_chunk = (size_t)cs * 256 * 2048 * 4;
        return 2 * wx_chunk + h_bytes + c_bytes + img_bytes;
    };

    // variable chunk schedule: small head chunk kills the pipeline bubble.
    int chunks[9]; int nch = 0; int csmax = 0;
    if (ws_size >= need_for(32)) {
        csmax = 32; nch = 5;
        chunks[0] = 4; chunks[1] = 28; chunks[2] = 32; chunks[3] = 32; chunks[4] = 32;
    } else if (ws_size >= need_for(16)) {
        csmax = 16; nch = 9;
        chunks[0] = 4; chunks[1] = 12;
        for (int i = 2; i < 9; ++i) chunks[i] = 16;
    }

    if (csmax) {
        const size_t wx_chunk = (size_t)csmax * 256 * 2048 * 4;
        char* p = (char*)d_ws;
        uint_t*   wxb[2] = { (uint_t*)p, (uint_t*)(p + wx_chunk) };
        ushort_t* hws    = (ushort_t*)(p + 2 * wx_chunk);
        float*    cws    = (float*)(p + 2 * wx_chunk + h_bytes);
        short8*   img    = (short8*)(p + 2 * wx_chunk + h_bytes + c_bytes);

        int off[10]; off[0] = 0;
        for (int i = 0; i < nch; ++i) off[i + 1] = off[i] + chunks[i];

        podcritic_prep<<<48, NT, 0, stream>>>(W1, W2, Wih, Whh, img);

        // head: enc chunk 0 alone (small -> tiny bubble)
        podcritic_step<<<128 * chunks[0], NT, 0, stream>>>(
            self_obs, tm_obs, en_obs, cp_obs, b1, b2, bih, bhh, img,
            wxb[0], wxb[0], hws, cws, Wv, bv, out,
            /*enc_c0=*/0, /*rec_c0=*/0, /*nrec=*/0, 0, 0, chunks[0]);

        for (int i = 0; i < nch; ++i) {
            int nenc = (i + 1 < nch) ? 128 * chunks[i + 1] : 0;
            int grid = 256 + nenc;
            podcritic_step<<<grid, NT, 0, stream>>>(
                self_obs, tm_obs, en_obs, cp_obs, b1, b2, bih, bhh, img,
                wxb[(i + 1) & 1], wxb[i & 1], hws, cws, Wv, bv, out,
                /*enc_c0=*/off[i + 1], /*rec_c0=*/off[i],
                /*nrec=*/256, (i == 0) ? 1 : 0, (i == nch - 1) ? 1 : 0, chunks[i]);
        }
    } else {
        podcritic_mfma<<<BB / NB, NT, 0, stream>>>(
            self_obs, tm_obs, en_obs, cp_obs,
            W1, b1, W2, b2, Wih, bih, Whh, bhh, Wv, bv, out);
    }
}

// Round 6
// 393.352 us; speedup vs baseline: 1.0100x; 1.0100x over previous
//
#include <hip/hip_runtime.h>
#include <hip/hip_bf16.h>

#define BB 4096
#define SS 128
#define NB 16
#define NT 256

typedef __attribute__((ext_vector_type(8))) short short8;
typedef __attribute__((ext_vector_type(4))) float f32x4;
typedef unsigned short ushort_t;
typedef unsigned int uint_t;

#define SX_STR   72
#define SH1_STR  264
#define SEMB_STR 136
#define SH_STR   72
#define ENC_LDS_USHORTS (32 * SH1_STR + 32 * SEMB_STR)   // 12800 -> 25.6 KB

// Native HW bf16 convert (RNE — identical rounding to the old bit-trick,
// 1 VALU instead of ~4). NOT inline asm (round-1 lesson): the compiler maps
// scalar casts to the HW instr itself (m240).
__device__ __forceinline__ ushort_t f2bf(float f) {
    union { __hip_bfloat16 b; ushort_t u; } x;
    x.b = __float2bfloat16(f);
    return x.u;
}
__device__ __forceinline__ uint_t pack2(float a, float b) {
    return (uint_t)f2bf(a) | ((uint_t)f2bf(b) << 16);
}
__device__ __forceinline__ float bflo(uint_t u) {
    union { unsigned u; float f; } x; x.u = u << 16; return x.f;
}
__device__ __forceinline__ float bfhi(uint_t u) {
    union { unsigned u; float f; } x; x.u = u & 0xFFFF0000u; return x.f;
}
__device__ __forceinline__ float bf2f(ushort_t h) {
    union { unsigned u; float f; } x; x.u = ((unsigned)h) << 16; return x.f;
}
__device__ __forceinline__ float fsig(float x) {
    return __builtin_amdgcn_rcpf(1.f + __expf(-x));
}
__device__ __forceinline__ float ftanh(float x) {
    return 1.f - 2.f * __builtin_amdgcn_rcpf(__expf(2.f * x) + 1.f);
}
// workgroup barrier WITHOUT vmcnt drain (LDS ordering only)
__device__ __forceinline__ void barrier_lgkm() {
    asm volatile("s_waitcnt lgkmcnt(0)\n\ts_barrier" ::: "memory");
}

union FragU { short8 v; ushort_t u[8]; };

// ============================================================================
// Prep: bf16 B-fragment images for W1/W2/Wih/Whh.
// ============================================================================
__global__ void podcritic_prep(const float* __restrict__ W1, const float* __restrict__ W2,
                               const float* __restrict__ Wih, const float* __restrict__ Whh,
                               short8* __restrict__ img)
{
    const int W = blockIdx.x * 4 + (threadIdx.x >> 6);   // 0..191
    const int l = threadIdx.x & 63;
    const int q = l >> 4, m = l & 15;
    FragU u;
    #pragma unroll
    for (int j = 0; j < 8; ++j) {
        float v;
        if (W < 32)       { int nt = W >> 1,        kk = W & 1;        int k = kk*32 + q*8 + j;
                            v = (k < 47) ? W1[k*256 + nt*16 + m] : 0.f; }
        else if (W < 96)  { int f = W - 32, nt = f >> 3, kk = f & 7;   int k = kk*32 + q*8 + j;
                            v = W2[k*128 + nt*16 + m]; }
        else if (W < 160) { int f = W - 96, nt = f >> 2, kk = f & 3;   int k = kk*32 + q*8 + j;
                            v = Wih[k*256 + nt*16 + m]; }
        else              { int f = W - 160, nt = f >> 1, kk = f & 1;  int k = kk*32 + q*8 + j;
                            v = Whh[k*256 + nt*16 + m]; }
        u.u[j] = f2bf(v);
    }
    img[W * 64 + l] = u.v;
}

// ============================================================================
// Encoder block: M=32 rows (2 steps x 16 batch), 3 lgkm barriers.
// Branchless gather; biases folded into accumulator init; per-phase
// fragment loads (compiler sinks them; keeps VGPR low).
// Works for any even chunk length cs: nenc = 128*cs blocks, ytile = e>>8.
// ============================================================================
__device__ __forceinline__ void enc_block(
    ushort_t* smem,
    const float* __restrict__ self_obs, const float* __restrict__ tm_obs,
    const float* __restrict__ en_obs,   const float* __restrict__ cp_obs,
    const float* __restrict__ b1, const float* __restrict__ b2,
    const float* __restrict__ bih, const float* __restrict__ bhh,
    const short8* __restrict__ img, uint_t* __restrict__ wx, int c0, int e)
{
    ushort_t* sh1 = smem;                     // 32*SH1_STR
    ushort_t* sxe = smem + 32 * SH1_STR;      // 32*SEMB_STR (x then emb)

    const int t = threadIdx.x;
    const int w = t >> 6, l = t & 63, q = l >> 4, m = l & 15;
    const int bg = e & 255, b0 = bg * NB;
    const int ytile = e >> 8;
    const int sbase = c0 + ytile * 2;

    // ---- branchless gather: resolve (ptr,stride,scale) once per lane ----
    {
        const int col = t & 63, rw0 = t >> 6;
        const float* p; int stride, soff; float scale;
        if (col < 15)      { p = self_obs + col;      stride = 15; soff = 0;  scale = 0.5f; }
        else if (col < 28) { p = tm_obs + (col - 15); stride = 13; soff = 0;  scale = 0.5f; }
        else if (col < 41) { p = en_obs + (col - 28); stride = 26; soff = 13; scale = 0.5f; }
        else if (col < 47) { p = cp_obs + (col - 41); stride = 6;  soff = 0;  scale = 0.5f; }
        else               { p = self_obs;            stride = 0;  soff = 0;  scale = 0.f; }
        #pragma unroll
        for (int jj = 0; jj < 8; ++jj) {
            int rr = 4 * jj + rw0;
            int mt = rr >> 4, r = rr & 15;
            int bs = (b0 + r) * SS + sbase + mt;
            int o = bs * stride;
            float v = scale * (p[o] + p[o + soff]);
            sxe[rr * SX_STR + col] = f2bf(v);
        }
    }
    float bias1[4], bias2[2], bgf[4];
    #pragma unroll
    for (int i = 0; i < 4; ++i) bias1[i] = b1[w * 64 + i * 16 + m];
    #pragma unroll
    for (int i = 0; i < 2; ++i) bias2[i] = b2[32 * w + 16 * i + m];
    #pragma unroll
    for (int i = 0; i < 4; ++i) { int n = (w + 4 * i) * 16 + m; bgf[i] = bih[n] + bhh[n]; }
    barrier_lgkm();

    // ---- phase 1: H1 = relu(x @ W1 + b1), M=32; bias in acc init ----
    {
        short8 w1f[4][2];
        #pragma unroll
        for (int i = 0; i < 4; ++i)
            #pragma unroll
            for (int kk = 0; kk < 2; ++kk)
                w1f[i][kk] = img[(((4 * w + i) * 2) + kk) * 64 + l];
        f32x4 c1[2][4];
        #pragma unroll
        for (int mt = 0; mt < 2; ++mt)
            #pragma unroll
            for (int i = 0; i < 4; ++i)
                c1[mt][i] = (f32x4){bias1[i], bias1[i], bias1[i], bias1[i]};
        #pragma unroll
        for (int kk = 0; kk < 2; ++kk) {
            #pragma unroll
            for (int mt = 0; mt < 2; ++mt) {
                short8 a = *(const short8*)&sxe[(mt * 16 + m) * SX_STR + kk * 32 + q * 8];
                #pragma unroll
                for (int i = 0; i < 4; ++i)
                    c1[mt][i] = __builtin_amdgcn_mfma_f32_16x16x32_bf16(a, w1f[i][kk], c1[mt][i], 0, 0, 0);
            }
        }
        #pragma unroll
        for (int mt = 0; mt < 2; ++mt)
            #pragma unroll
            for (int i = 0; i < 4; ++i) {
                int col = w * 64 + i * 16 + m;
                #pragma unroll
                for (int r = 0; r < 4; ++r)
                    sh1[(mt * 16 + q * 4 + r) * SH1_STR + col] = f2bf(fmaxf(c1[mt][i][r], 0.f));
            }
    }
    barrier_lgkm();

    // ---- phase 2: EMB = relu(H1 @ W2 + b2); bias in acc init ----
    {
        short8 w2f[2][8];
        #pragma unroll
        for (int i = 0; i < 2; ++i)
            #pragma unroll
            for (int kk = 0; kk < 8; ++kk)
                w2f[i][kk] = img[(32 + ((2 * w + i) * 8) + kk) * 64 + l];
        f32x4 c2[2][2];
        #pragma unroll
        for (int mt = 0; mt < 2; ++mt)
            #pragma unroll
            for (int i = 0; i < 2; ++i)
                c2[mt][i] = (f32x4){bias2[i], bias2[i], bias2[i], bias2[i]};
        #pragma unroll
        for (int kk = 0; kk < 8; ++kk) {
            #pragma unroll
            for (int mt = 0; mt < 2; ++mt) {
                short8 a = *(const short8*)&sh1[(mt * 16 + m) * SH1_STR + kk * 32 + q * 8];
                #pragma unroll
                for (int i = 0; i < 2; ++i)
                    c2[mt][i] = __builtin_amdgcn_mfma_f32_16x16x32_bf16(a, w2f[i][kk], c2[mt][i], 0, 0, 0);
            }
        }
        #pragma unroll
        for (int mt = 0; mt < 2; ++mt)
            #pragma unroll
            for (int i = 0; i < 2; ++i) {
                int col = 32 * w + 16 * i + m;
                #pragma unroll
                for (int r = 0; r < 4; ++r)
                    sxe[(mt * 16 + q * 4 + r) * SEMB_STR + col] = f2bf(fmaxf(c2[mt][i][r], 0.f));
            }
    }
    barrier_lgkm();

    // ---- phase 3: wx = emb @ Wih + (bih+bhh), swizzled store ----
    {
        short8 wihf[4][4];
        #pragma unroll
        for (int i = 0; i < 4; ++i)
            #pragma unroll
            for (int kk = 0; kk < 4; ++kk)
                wihf[i][kk] = img[(96 + ((w + 4 * i) * 4) + kk) * 64 + l];
        #pragma unroll
        for (int mt = 0; mt < 2; ++mt) {
            f32x4 g[4];
            #pragma unroll
            for (int i = 0; i < 4; ++i) g[i] = (f32x4){bgf[i], bgf[i], bgf[i], bgf[i]};
            #pragma unroll
            for (int kk = 0; kk < 4; ++kk) {
                short8 a = *(const short8*)&sxe[(mt * 16 + m) * SEMB_STR + kk * 32 + q * 8];
                #pragma unroll
                for (int i = 0; i < 4; ++i)
                    g[i] = __builtin_amdgcn_mfma_f32_16x16x32_bf16(a, wihf[i][kk], g[i], 0, 0, 0);
            }
            int slc = ytile * 2 + mt;
            uint_t* dst = wx + (size_t)(slc * 256 + bg) * 2048 + l * 2;
            #pragma unroll
            for (int i = 0; i < 4; ++i) {
                uint2 vv;
                vv.x = pack2(g[i][0], g[i][1]);
                vv.y = pack2(g[i][2], g[i][3]);
                *(uint2*)(dst + (w + 4 * i) * 128) = vv;
            }
        }
    }
}

// ============================================================================
// Recurrence block with FUSED value head (paired every 2 steps):
// 4 waves / 16 batch rows, 1 lgkm barrier/step, 2-deep wx prefetch.
// ============================================================================
__device__ __forceinline__ void rec_block(
    ushort_t* smem,
    const short8* __restrict__ whhimg, const uint_t* __restrict__ wx,
    ushort_t* __restrict__ hws, float* __restrict__ cws,
    const float* __restrict__ Wv, const float* __restrict__ bv,
    float* __restrict__ out, int rc0, int first, int last, int csr)
{
    const int t = threadIdx.x;
    const int w = t >> 6, l = t & 63, q = l >> 4, m = l & 15;
    const int bg = blockIdx.x, b0 = bg * NB;
    const int vr = t >> 4, vp = t & 15;           // value-head row / col-group

    short8 whhf[4][2];
    #pragma unroll
    for (int a = 0; a < 4; ++a)
        #pragma unroll
        for (int kk = 0; kk < 2; ++kk)
            whhf[a][kk] = whhimg[(((w + 4 * a) * 2) + kk) * 64 + l];

    const float4 wv = *(const float4*)(Wv + vp * 4);
    const float bvv = bv[0];

    float creg[4], hlast[4] = {0.f, 0.f, 0.f, 0.f};
    if (first) {
        #pragma unroll
        for (int r = 0; r < 4; ++r) creg[r] = 0.f;
        int idx4 = t * 4, row = idx4 >> 6, col = idx4 & 63;
        uint2 z; z.x = 0u; z.y = 0u;
        *(uint2*)&smem[row * SH_STR + col] = z;
    } else {
        int idx4 = t * 4, row = idx4 >> 6, col = idx4 & 63;
        uint2 hv2 = *(const uint2*)((const uint_t*)(hws + (size_t)bg * 1024 + idx4));
        *(uint2*)&smem[row * SH_STR + col] = hv2;
        float4 cv = *(const float4*)(cws + ((size_t)bg * 256 + t) * 4);
        creg[0] = cv.x; creg[1] = cv.y; creg[2] = cv.z; creg[3] = cv.w;
    }

    uint2 upf[2][4];
    {
        const uint_t* p0 = wx + (size_t)(0 * 256 + bg) * 2048 + l * 2;
        const uint_t* p1 = wx + (size_t)(1 * 256 + bg) * 2048 + l * 2;
        #pragma unroll
        for (int a = 0; a < 4; ++a) {
            upf[0][a] = *(const uint2*)(p0 + (w + 4 * a) * 128);
            upf[1][a] = *(const uint2*)(p1 + (w + 4 * a) * 128);
        }
    }

    barrier_lgkm();

    // core of one step (PAR = buffer parity, SLV = step index); no val head.
    #define REC_CORE(PAR, SLV)                                                          \
        const int sl_ = (SLV);                                                          \
        ushort_t* shc = smem + (PAR) * (NB * SH_STR);                                   \
        ushort_t* shn = smem + (1 - (PAR)) * (NB * SH_STR);                             \
        short8 af0 = *(const short8*)&shc[m * SH_STR + q * 8];                          \
        short8 af1 = *(const short8*)&shc[m * SH_STR + 32 + q * 8];                     \
        f32x4 g[4];                                                                     \
        _Pragma("unroll")                                                               \
        for (int a = 0; a < 4; ++a) {                                                   \
            g[a][0] = bflo(upf[PAR][a].x); g[a][1] = bfhi(upf[PAR][a].x);               \
            g[a][2] = bflo(upf[PAR][a].y); g[a][3] = bfhi(upf[PAR][a].y);               \
        }                                                                               \
        {                                                                               \
            int snext = (sl_ + 2 < csr) ? (sl_ + 2) : sl_;                              \
            const uint_t* pn = wx + (size_t)(snext * 256 + bg) * 2048 + l * 2;          \
            _Pragma("unroll")                                                           \
            for (int a = 0; a < 4; ++a)                                                 \
                upf[PAR][a] = *(const uint2*)(pn + (w + 4 * a) * 128);                  \
        }                                                                               \
        _Pragma("unroll")                                                               \
        for (int a = 0; a < 4; ++a) {                                                   \
            g[a] = __builtin_amdgcn_mfma_f32_16x16x32_bf16(af0, whhf[a][0], g[a], 0, 0, 0); \
            g[a] = __builtin_amdgcn_mfma_f32_16x16x32_bf16(af1, whhf[a][1], g[a], 0, 0, 0); \
        }                                                                               \
        _Pragma("unroll")                                                               \
        for (int r = 0; r < 4; ++r) {                                                   \
            float gi = fsig(g[0][r]);                                                   \
            float gf = fsig(g[1][r]);                                                   \
            float gg = ftanh(g[2][r]);                                                  \
            float go = fsig(g[3][r]);                                                   \
            float c  = gf * creg[r] + gi * gg;                                          \
            creg[r] = c;                                                                \
            float h = go * ftanh(c);                                                    \
            hlast[r] = h;                                                               \
            shn[(q * 4 + r) * SH_STR + 16 * w + m] = f2bf(h);                           \
        }

    for (int sl = 0; sl < csr; sl += 2) {
        {   // even step (PAR=0): compute only
            REC_CORE(0, sl);
            barrier_lgkm();
        }
        {   // odd step (PAR=1): compute + dual val head for steps sl, sl+1
            // early read of h(sl) from shc (stable until step sl+2's writes,
            // which happen after the next barrier)
            uint2 hvA = *(const uint2*)&smem[1 * (NB * SH_STR) + vr * SH_STR + vp * 4];
            REC_CORE(1, sl + 1);
            barrier_lgkm();
            uint2 hvB = *(const uint2*)&shn[vr * SH_STR + vp * 4];   // h(sl+1)
            float pvA = bflo(hvA.x) * wv.x + bfhi(hvA.x) * wv.y
                      + bflo(hvA.y) * wv.z + bfhi(hvA.y) * wv.w;
            float pvB = bflo(hvB.x) * wv.x + bfhi(hvB.x) * wv.y
                      + bflo(hvB.y) * wv.z + bfhi(hvB.y) * wv.w;
            pvA += __shfl_xor(pvA, 1, 16);  pvB += __shfl_xor(pvB, 1, 16);
            pvA += __shfl_xor(pvA, 2, 16);  pvB += __shfl_xor(pvB, 2, 16);
            pvA += __shfl_xor(pvA, 4, 16);  pvB += __shfl_xor(pvB, 4, 16);
            pvA += __shfl_xor(pvA, 8, 16);  pvB += __shfl_xor(pvB, 8, 16);
            if (vp == 0) {
                float2 o; o.x = pvA + bvv; o.y = pvB + bvv;
                *(float2*)&out[(size_t)(b0 + vr) * SS + rc0 + sl_ - 1] = o;
            }
        }
    }
    #undef REC_CORE

    if (!last) {
        const int jcol = 16 * w + m;
        #pragma unroll
        for (int r = 0; r < 4; ++r)
            hws[(size_t)bg * 1024 + (q * 4 + r) * 64 + jcol] = f2bf(hlast[r]);
        float4 cv; cv.x = creg[0]; cv.y = creg[1]; cv.z = creg[2]; cv.w = creg[3];
        *(float4*)(cws + ((size_t)bg * 256 + t) * 4) = cv;
    } else {
        const int jcol = 16 * w + m;
        #pragma unroll
        for (int r = 0; r < 4; ++r) {
            int row = b0 + q * 4 + r;
            out[BB * SS + (size_t)row * 64 + jcol]           = hlast[r];
            out[BB * SS + BB * 64 + (size_t)row * 64 + jcol] = creg[r];
        }
    }
}

// ============================================================================
// Combined pipeline dispatch: [0,nrec) rec(chunk i)+fused-val | rest enc(i+1).
// ============================================================================
__global__ __launch_bounds__(NT, 4)
void podcritic_step(const float* __restrict__ self_obs, const float* __restrict__ tm_obs,
                    const float* __restrict__ en_obs,   const float* __restrict__ cp_obs,
                    const float* __restrict__ b1, const float* __restrict__ b2,
                    const float* __restrict__ bih, const float* __restrict__ bhh,
                    const short8* __restrict__ img,
                    uint_t* __restrict__ wx_enc, const uint_t* __restrict__ wx_rec,
                    ushort_t* __restrict__ hws, float* __restrict__ cws,
                    const float* __restrict__ Wv, const float* __restrict__ bv,
                    float* __restrict__ out,
                    int enc_c0, int rec_c0, int nrec, int first, int last, int rec_cs)
{
    __shared__ __align__(16) ushort_t smem[ENC_LDS_USHORTS];
    const int bid = blockIdx.x;
    if (bid < nrec) {
        rec_block(smem, img + 160 * 64, wx_rec, hws, cws, Wv, bv, out,
                  rec_c0, first, last, rec_cs);
    } else {
        enc_block(smem, self_obs, tm_obs, en_obs, cp_obs, b1, b2, bih, bhh,
                  img, wx_enc, enc_c0, bid - nrec);
    }
}

// ============================================================================
// Fallback: fused kernel (only if ws too small) — round-2 structure.
// ============================================================================
__global__ __launch_bounds__(NT, 1)
void podcritic_mfma(const float* __restrict__ self_obs,
                    const float* __restrict__ tm_obs,
                    const float* __restrict__ en_obs,
                    const float* __restrict__ cp_obs,
                    const float* __restrict__ W1, const float* __restrict__ b1,
                    const float* __restrict__ W2, const float* __restrict__ b2,
                    const float* __restrict__ Wih, const float* __restrict__ bih,
                    const float* __restrict__ Whh, const float* __restrict__ bhh,
                    const float* __restrict__ Wv, const float* __restrict__ bv,
                    float* __restrict__ out)
{
    __shared__ __align__(16) ushort_t sx[2][NB * SX_STR];
    __shared__ __align__(16) ushort_t sh1[NB * SH1_STR];
    __shared__ __align__(16) ushort_t semb[NB * SEMB_STR];
    __shared__ __align__(16) ushort_t sh[NB * SH_STR];
    __shared__ float sWv[64];

    const int t  = threadIdx.x;
    const int w  = t >> 6;
    const int l  = t & 63;
    const int q  = l >> 4;
    const int m  = l & 15;
    const int b0 = blockIdx.x * NB;

    short8 w1f[4][2];
    short8 w2f[2][8];
    short8 wihf[4][4];
    short8 whhf[4][2];
    float bias1[4], bias2[2], bg[4];

    #pragma unroll
    for (int i = 0; i < 4; ++i) {
        int n = w * 64 + i * 16 + m;
        bias1[i] = b1[n];
        #pragma unroll
        for (int kk = 0; kk < 2; ++kk) {
            FragU u;
            #pragma unroll
            for (int j = 0; j < 8; ++j) {
                int k = kk * 32 + q * 8 + j;
                u.u[j] = f2bf(k < 47 ? W1[k * 256 + n] : 0.f);
            }
            w1f[i][kk] = u.v;
        }
    }
    #pragma unroll
    for (int i = 0; i < 2; ++i) {
        int n = 32 * w + i * 16 + m;
        bias2[i] = b2[n];
        #pragma unroll
        for (int kk = 0; kk < 8; ++kk) {
            FragU u;
            #pragma unroll
            for (int j = 0; j < 8; ++j) {
                int k = kk * 32 + q * 8 + j;
                u.u[j] = f2bf(W2[k * 128 + n]);
            }
            w2f[i][kk] = u.v;
        }
    }
    #pragma unroll
    for (int i = 0; i < 4; ++i) {
        int n = (w + 4 * i) * 16 + m;
        bg[i] = bih[n] + bhh[n];
        #pragma unroll
        for (int kk = 0; kk < 4; ++kk) {
            FragU u;
            #pragma unroll
            for (int j = 0; j < 8; ++j) {
                int k = kk * 32 + q * 8 + j;
                u.u[j] = f2bf(Wih[k * 256 + n]);
            }
            wihf[i][kk] = u.v;
        }
        #pragma unroll
        for (int kk = 0; kk < 2; ++kk) {
            FragU u;
            #pragma unroll
            for (int j = 0; j < 8; ++j) {
                int k = kk * 32 + q * 8 + j;
                u.u[j] = f2bf(Whh[k * 256 + n]);
            }
            whhf[i][kk] = u.v;
        }
    }
    const float bvv = bv[0];
    if (t < 64) sWv[t] = Wv[t];

    for (int idx = t; idx < NB * SH_STR; idx += NT) sh[idx] = 0;

    const int pcol = t & 63;
    const int prow = t >> 6;
    #pragma unroll
    for (int j = 0; j < 4; ++j) {
        int r  = 4 * j + prow;
        int bs = (b0 + r) * SS + 0;
        float v = 0.f;
        if (pcol < 15)      v = self_obs[bs * 15 + pcol];
        else if (pcol < 28) v = tm_obs[bs * 13 + (pcol - 15)];
        else if (pcol < 41) { int kk = pcol - 28;
                              v = 0.5f * (en_obs[(bs * 2) * 13 + kk] + en_obs[(bs * 2) * 13 + 13 + kk]); }
        else if (pcol < 47) v = cp_obs[bs * 6 + (pcol - 41)];
        sx[0][r * SX_STR + pcol] = f2bf(v);
    }
    __syncthreads();

    float creg[4] = {0.f, 0.f, 0.f, 0.f};
    float hreg[4] = {0.f, 0.f, 0.f, 0.f};
    int cur = 0;

    for (int s = 0; s < SS; ++s) {
        float pf[4];
        #pragma unroll
        for (int j = 0; j < 4; ++j) {
            float v = 0.f;
            if (s + 1 < SS) {
                int r  = 4 * j + prow;
                int bs = (b0 + r) * SS + (s + 1);
                if (pcol < 15)      v = self_obs[bs * 15 + pcol];
                else if (pcol < 28) v = tm_obs[bs * 13 + (pcol - 15)];
                else if (pcol < 41) { int kk = pcol - 28;
                                      v = 0.5f * (en_obs[(bs * 2) * 13 + kk] + en_obs[(bs * 2) * 13 + 13 + kk]); }
                else if (pcol < 47) v = cp_obs[bs * 6 + (pcol - 41)];
            }
            pf[j] = v;
        }

        {
            f32x4 c1[4] = {{0,0,0,0},{0,0,0,0},{0,0,0,0},{0,0,0,0}};
            #pragma unroll
            for (int kk = 0; kk < 2; ++kk) {
                short8 a = *(const short8*)&sx[cur][m * SX_STR + kk * 32 + q * 8];
                #pragma unroll
                for (int i = 0; i < 4; ++i)
                    c1[i] = __builtin_amdgcn_mfma_f32_16x16x32_bf16(a, w1f[i][kk], c1[i], 0, 0, 0);
            }
            #pragma unroll
            for (int i = 0; i < 4; ++i) {
                int col = w * 64 + i * 16 + m;
                #pragma unroll
                for (int r = 0; r < 4; ++r)
                    sh1[(q * 4 + r) * SH1_STR + col] = f2bf(fmaxf(c1[i][r] + bias1[i], 0.f));
            }
        }
        __syncthreads();

        {
            f32x4 c2[2] = {{0,0,0,0},{0,0,0,0}};
            #pragma unroll
            for (int kk = 0; kk < 8; ++kk) {
                short8 a = *(const short8*)&sh1[m * SH1_STR + kk * 32 + q * 8];
                #pragma unroll
                for (int i = 0; i < 2; ++i)
                    c2[i] = __builtin_amdgcn_mfma_f32_16x16x32_bf16(a, w2f[i][kk], c2[i], 0, 0, 0);
            }
            #pragma unroll
            for (int i = 0; i < 2; ++i) {
                int col = 32 * w + i * 16 + m;
                #pragma unroll
                for (int r = 0; r < 4; ++r)
                    semb[(q * 4 + r) * SEMB_STR + col] = f2bf(fmaxf(c2[i][r] + bias2[i], 0.f));
            }
        }
        __syncthreads();

        {
            f32x4 g[4];
            #pragma unroll
            for (int i = 0; i < 4; ++i) g[i] = (f32x4){bg[i], bg[i], bg[i], bg[i]};
            #pragma unroll
            for (int kk = 0; kk < 4; ++kk) {
                short8 a = *(const short8*)&semb[m * SEMB_STR + kk * 32 + q * 8];
                #pragma unroll
                for (int i = 0; i < 4; ++i)
                    g[i] = __builtin_amdgcn_mfma_f32_16x16x32_bf16(a, wihf[i][kk], g[i], 0, 0, 0);
            }
            #pragma unroll
            for (int kk = 0; kk < 2; ++kk) {
                short8 a = *(const short8*)&sh[m * SH_STR + kk * 32 + q * 8];
                #pragma unroll
                for (int i = 0; i < 4; ++i)
                    g[i] = __builtin_amdgcn_mfma_f32_16x16x32_bf16(a, whhf[i][kk], g[i], 0, 0, 0);
            }
            const int jcol = 16 * w + m;
            #pragma unroll
            for (int r = 0; r < 4; ++r) {
                float gi = fsig(g[0][r]);
                float gf = fsig(g[1][r]);
                float gg = ftanh(g[2][r]);
                float go = fsig(g[3][r]);
                float c  = gf * creg[r] + gi * gg;
                creg[r] = c;
                float h = go * ftanh(c);
                hreg[r] = h;
                sh[(q * 4 + r) * SH_STR + jcol] = f2bf(h);
            }
            #pragma unroll
            for (int j = 0; j < 4; ++j) {
                int r = 4 * j + prow;
                sx[cur ^ 1][r * SX_STR + pcol] = f2bf(pf[j]);
            }
        }
        __syncthreads();

        {
            int r = t >> 4, pp = t & 15;
            const ushort_t* hp = &sh[r * SH_STR + pp * 4];
            float pv = 0.f;
            #pragma unroll
            for (int j = 0; j < 4; ++j) pv += bf2f(hp[j]) * sWv[pp * 4 + j];
            pv += __shfl_xor(pv, 1, 16);
            pv += __shfl_xor(pv, 2, 16);
            pv += __shfl_xor(pv, 4, 16);
            pv += __shfl_xor(pv, 8, 16);
            if (pp == 0) out[(b0 + r) * SS + s] = pv + bvv;
        }
        cur ^= 1;
    }

    {
        const int jcol = 16 * w + m;
        #pragma unroll
        for (int r = 0; r < 4; ++r) {
            int row = b0 + q * 4 + r;
            out[BB * SS + row * 64 + jcol]           = hreg[r];
            out[BB * SS + BB * 64 + row * 64 + jcol] = creg[r];
        }
    }
}

extern "C" void kernel_launch(void* const* d_in, const int* in_sizes, int n_in,
                              void* d_out, int out_size, void* d_ws, size_t ws_size,
                              hipStream_t stream) {
    const float* self_obs = (const float*)d_in[0];
    const float* tm_obs   = (const float*)d_in[1];
    const float* en_obs   = (const float*)d_in[2];
    const float* cp_obs   = (const float*)d_in[3];
    const float* W1  = (const float*)d_in[4];
    const float* b1  = (const float*)d_in[5];
    const float* W2  = (const float*)d_in[6];
    const float* b2  = (const float*)d_in[7];
    const float* Wih = (const float*)d_in[8];
    const float* bih = (const float*)d_in[9];
    const float* Whh = (const float*)d_in[10];
    const float* bhh = (const float*)d_in[11];
    const float* Wv  = (const float*)d_in[12];
    const float* bv  = (const float*)d_in[13];
    float* out = (float*)d_out;

    const size_t h_bytes   = 256 * 1024 * 2;                // 524,288
    const size_t c_bytes   = 256 * 1024 * 4;                // 1,048,576
    const size_t img_bytes = 192 * 64 * 16;                 // 196,608

    auto need_for = [&](int cs) -> size_t {
        size_t wx_chunk = (size_t)cs * 256 * 2048 * 4;
        return 2 * wx_chunk + h_bytes + c_bytes + img_bytes;
    };

    // variable chunk schedule: small head chunk kills the pipeline bubble,
    // small TAIL chunk kills the rec-only drain (rec(4) ~9us vs rec(32) ~60us).
    int chunks[10]; int nch = 0; int csmax = 0;
    if (ws_size >= need_for(32)) {
        csmax = 32; nch = 6;
        chunks[0] = 4; chunks[1] = 28; chunks[2] = 32;
        chunks[3] = 32; chunks[4] = 28; chunks[5] = 4;
    } else if (ws_size >= need_for(16)) {
        csmax = 16; nch = 10;
        chunks[0] = 4; chunks[1] = 12;
        for (int i = 2; i < 8; ++i) chunks[i] = 16;
        chunks[8] = 12; chunks[9] = 4;
    }

    if (csmax) {
        const size_t wx_chunk = (size_t)csmax * 256 * 2048 * 4;
        char* p = (char*)d_ws;
        uint_t*   wxb[2] = { (uint_t*)p, (uint_t*)(p + wx_chunk) };
        ushort_t* hws    = (ushort_t*)(p + 2 * wx_chunk);
        float*    cws    = (float*)(p + 2 * wx_chunk + h_bytes);
        short8*   img    = (short8*)(p + 2 * wx_chunk + h_bytes + c_bytes);

        int off[11]; off[0] = 0;
        for (int i = 0; i < nch; ++i) off[i + 1] = off[i] + chunks[i];

        podcritic_prep<<<48, NT, 0, stream>>>(W1, W2, Wih, Whh, img);

        // head: enc chunk 0 alone (small -> tiny bubble)
        podcritic_step<<<128 * chunks[0], NT, 0, stream>>>(
            self_obs, tm_obs, en_obs, cp_obs, b1, b2, bih, bhh, img,
            wxb[0], wxb[0], hws, cws, Wv, bv, out,
            /*enc_c0=*/0, /*rec_c0=*/0, /*nrec=*/0, 0, 0, chunks[0]);

        for (int i = 0; i < nch; ++i) {
            int nenc = (i + 1 < nch) ? 128 * chunks[i + 1] : 0;
            int grid = 256 + nenc;
            podcritic_step<<<grid, NT, 0, stream>>>(
                self_obs, tm_obs, en_obs, cp_obs, b1, b2, bih, bhh, img,
                wxb[(i + 1) & 1], wxb[i & 1], hws, cws, Wv, bv, out,
                /*enc_c0=*/off[i + 1], /*rec_c0=*/off[i],
                /*nrec=*/256, (i == 0) ? 1 : 0, (i == nch - 1) ? 1 : 0, chunks[i]);
        }
    } else {
        podcritic_mfma<<<BB / NB, NT, 0, stream>>>(
            self_obs, tm_obs, en_obs, cp_obs,
            W1, b1, W2, b2, Wih, bih, Whh, bhh, Wv, bv, out);
    }
}

// Round 7
// 364.204 us; speedup vs baseline: 1.0908x; 1.0800x over previous
//
#include <hip/hip_runtime.h>
#include <hip/hip_bf16.h>

#define BB 4096
#define SS 128
#define NB 16
#define NT 256

typedef __attribute__((ext_vector_type(8))) short short8;
typedef __attribute__((ext_vector_type(4))) float f32x4;
typedef unsigned short ushort_t;
typedef unsigned int uint_t;

#define SX_STR   72
#define SH1_STR  264
#define SEMB_STR 136
#define SH_STR   72
// M=64 enc tile: 64 rows (4 steps x 16 batch) -> 51.2 KB, 3 blocks/CU.
#define ENC_LDS_USHORTS (64 * SH1_STR + 64 * SEMB_STR)   // 25600 -> 51.2 KB

// Native HW bf16 convert (RNE — identical rounding to the old bit-trick).
__device__ __forceinline__ ushort_t f2bf(float f) {
    union { __hip_bfloat16 b; ushort_t u; } x;
    x.b = __float2bfloat16(f);
    return x.u;
}
__device__ __forceinline__ uint_t pack2(float a, float b) {
    return (uint_t)f2bf(a) | ((uint_t)f2bf(b) << 16);
}
__device__ __forceinline__ float bflo(uint_t u) {
    union { unsigned u; float f; } x; x.u = u << 16; return x.f;
}
__device__ __forceinline__ float bfhi(uint_t u) {
    union { unsigned u; float f; } x; x.u = u & 0xFFFF0000u; return x.f;
}
__device__ __forceinline__ float bf2f(ushort_t h) {
    union { unsigned u; float f; } x; x.u = ((unsigned)h) << 16; return x.f;
}
__device__ __forceinline__ float fsig(float x) {
    return __builtin_amdgcn_rcpf(1.f + __expf(-x));
}
__device__ __forceinline__ float ftanh(float x) {
    return 1.f - 2.f * __builtin_amdgcn_rcpf(__expf(2.f * x) + 1.f);
}
// workgroup barrier WITHOUT vmcnt drain (LDS ordering only)
__device__ __forceinline__ void barrier_lgkm() {
    asm volatile("s_waitcnt lgkmcnt(0)\n\ts_barrier" ::: "memory");
}

union FragU { short8 v; ushort_t u[8]; };

// ============================================================================
// Prep: bf16 B-fragment images for W1/W2/Wih/Whh.
// ============================================================================
__global__ void podcritic_prep(const float* __restrict__ W1, const float* __restrict__ W2,
                               const float* __restrict__ Wih, const float* __restrict__ Whh,
                               short8* __restrict__ img)
{
    const int W = blockIdx.x * 4 + (threadIdx.x >> 6);   // 0..191
    const int l = threadIdx.x & 63;
    const int q = l >> 4, m = l & 15;
    FragU u;
    #pragma unroll
    for (int j = 0; j < 8; ++j) {
        float v;
        if (W < 32)       { int nt = W >> 1,        kk = W & 1;        int k = kk*32 + q*8 + j;
                            v = (k < 47) ? W1[k*256 + nt*16 + m] : 0.f; }
        else if (W < 96)  { int f = W - 32, nt = f >> 3, kk = f & 7;   int k = kk*32 + q*8 + j;
                            v = W2[k*128 + nt*16 + m]; }
        else if (W < 160) { int f = W - 96, nt = f >> 2, kk = f & 3;   int k = kk*32 + q*8 + j;
                            v = Wih[k*256 + nt*16 + m]; }
        else              { int f = W - 160, nt = f >> 1, kk = f & 1;  int k = kk*32 + q*8 + j;
                            v = Whh[k*256 + nt*16 + m]; }
        u.u[j] = f2bf(v);
    }
    img[W * 64 + l] = u.v;
}

// ============================================================================
// Encoder block, M=64 (4 steps x 16 batch), 3 lgkm barriers.
// Doubles MFMA work per 160KB weight-fragment stream (the L2-bound resource):
// weight traffic per output element halves vs M=32. 51.2KB LDS, 3 blocks/CU.
// Requires chunk length divisible by 4; nenc = 64*cs, ytile = e>>8 spans 4
// steps. Arithmetic per element identical to M=32 version.
// ============================================================================
__device__ __forceinline__ void enc_block(
    ushort_t* smem,
    const float* __restrict__ self_obs, const float* __restrict__ tm_obs,
    const float* __restrict__ en_obs,   const float* __restrict__ cp_obs,
    const float* __restrict__ b1, const float* __restrict__ b2,
    const float* __restrict__ bih, const float* __restrict__ bhh,
    const short8* __restrict__ img, uint_t* __restrict__ wx, int c0, int e)
{
    ushort_t* sh1 = smem;                     // 64*SH1_STR
    ushort_t* sxe = smem + 64 * SH1_STR;      // 64*SEMB_STR (x then emb)

    const int t = threadIdx.x;
    const int w = t >> 6, l = t & 63, q = l >> 4, m = l & 15;
    const int bg = e & 255, b0 = bg * NB;
    const int ytile = e >> 8;                 // 0..cs/4-1
    const int sbase = c0 + ytile * 4;

    // ---- branchless gather: 64 rows = (step mt 0..3) x (batch r 0..15) ----
    {
        const int col = t & 63, rw0 = t >> 6;
        const float* p; int stride, soff; float scale;
        if (col < 15)      { p = self_obs + col;      stride = 15; soff = 0;  scale = 0.5f; }
        else if (col < 28) { p = tm_obs + (col - 15); stride = 13; soff = 0;  scale = 0.5f; }
        else if (col < 41) { p = en_obs + (col - 28); stride = 26; soff = 13; scale = 0.5f; }
        else if (col < 47) { p = cp_obs + (col - 41); stride = 6;  soff = 0;  scale = 0.5f; }
        else               { p = self_obs;            stride = 0;  soff = 0;  scale = 0.f; }
        #pragma unroll
        for (int jj = 0; jj < 16; ++jj) {
            int rr = 4 * jj + rw0;            // 0..63
            int mt = rr >> 4, r = rr & 15;
            int bs = (b0 + r) * SS + sbase + mt;
            int o = bs * stride;
            float v = scale * (p[o] + p[o + soff]);
            sxe[rr * SX_STR + col] = f2bf(v);
        }
    }
    float bias1[4], bias2[2], bgf[4];
    #pragma unroll
    for (int i = 0; i < 4; ++i) bias1[i] = b1[w * 64 + i * 16 + m];
    #pragma unroll
    for (int i = 0; i < 2; ++i) bias2[i] = b2[32 * w + 16 * i + m];
    #pragma unroll
    for (int i = 0; i < 4; ++i) { int n = (w + 4 * i) * 16 + m; bgf[i] = bih[n] + bhh[n]; }
    barrier_lgkm();

    // ---- phase 1: H1 = relu(x @ W1 + b1), M=64; bias in acc init ----
    {
        short8 w1f[4][2];
        #pragma unroll
        for (int i = 0; i < 4; ++i)
            #pragma unroll
            for (int kk = 0; kk < 2; ++kk)
                w1f[i][kk] = img[(((4 * w + i) * 2) + kk) * 64 + l];
        f32x4 c1[4][4];
        #pragma unroll
        for (int mt = 0; mt < 4; ++mt)
            #pragma unroll
            for (int i = 0; i < 4; ++i)
                c1[mt][i] = (f32x4){bias1[i], bias1[i], bias1[i], bias1[i]};
        #pragma unroll
        for (int kk = 0; kk < 2; ++kk) {
            #pragma unroll
            for (int mt = 0; mt < 4; ++mt) {
                short8 a = *(const short8*)&sxe[(mt * 16 + m) * SX_STR + kk * 32 + q * 8];
                #pragma unroll
                for (int i = 0; i < 4; ++i)
                    c1[mt][i] = __builtin_amdgcn_mfma_f32_16x16x32_bf16(a, w1f[i][kk], c1[mt][i], 0, 0, 0);
            }
        }
        #pragma unroll
        for (int mt = 0; mt < 4; ++mt)
            #pragma unroll
            for (int i = 0; i < 4; ++i) {
                int col = w * 64 + i * 16 + m;
                #pragma unroll
                for (int r = 0; r < 4; ++r)
                    sh1[(mt * 16 + q * 4 + r) * SH1_STR + col] = f2bf(fmaxf(c1[mt][i][r], 0.f));
            }
    }
    barrier_lgkm();

    // ---- phase 2: EMB = relu(H1 @ W2 + b2); bias in acc init ----
    {
        short8 w2f[2][8];
        #pragma unroll
        for (int i = 0; i < 2; ++i)
            #pragma unroll
            for (int kk = 0; kk < 8; ++kk)
                w2f[i][kk] = img[(32 + ((2 * w + i) * 8) + kk) * 64 + l];
        f32x4 c2[4][2];
        #pragma unroll
        for (int mt = 0; mt < 4; ++mt)
            #pragma unroll
            for (int i = 0; i < 2; ++i)
                c2[mt][i] = (f32x4){bias2[i], bias2[i], bias2[i], bias2[i]};
        #pragma unroll
        for (int kk = 0; kk < 8; ++kk) {
            #pragma unroll
            for (int mt = 0; mt < 4; ++mt) {
                short8 a = *(const short8*)&sh1[(mt * 16 + m) * SH1_STR + kk * 32 + q * 8];
                #pragma unroll
                for (int i = 0; i < 2; ++i)
                    c2[mt][i] = __builtin_amdgcn_mfma_f32_16x16x32_bf16(a, w2f[i][kk], c2[mt][i], 0, 0, 0);
            }
        }
        #pragma unroll
        for (int mt = 0; mt < 4; ++mt)
            #pragma unroll
            for (int i = 0; i < 2; ++i) {
                int col = 32 * w + 16 * i + m;
                #pragma unroll
                for (int r = 0; r < 4; ++r)
                    sxe[(mt * 16 + q * 4 + r) * SEMB_STR + col] = f2bf(fmaxf(c2[mt][i][r], 0.f));
            }
    }
    barrier_lgkm();

    // ---- phase 3: wx = emb @ Wih + (bih+bhh), swizzled store ----
    {
        short8 wihf[4][4];
        #pragma unroll
        for (int i = 0; i < 4; ++i)
            #pragma unroll
            for (int kk = 0; kk < 4; ++kk)
                wihf[i][kk] = img[(96 + ((w + 4 * i) * 4) + kk) * 64 + l];
        #pragma unroll
        for (int mt = 0; mt < 4; ++mt) {
            f32x4 g[4];
            #pragma unroll
            for (int i = 0; i < 4; ++i) g[i] = (f32x4){bgf[i], bgf[i], bgf[i], bgf[i]};
            #pragma unroll
            for (int kk = 0; kk < 4; ++kk) {
                short8 a = *(const short8*)&sxe[(mt * 16 + m) * SEMB_STR + kk * 32 + q * 8];
                #pragma unroll
                for (int i = 0; i < 4; ++i)
                    g[i] = __builtin_amdgcn_mfma_f32_16x16x32_bf16(a, wihf[i][kk], g[i], 0, 0, 0);
            }
            int slc = ytile * 4 + mt;
            uint_t* dst = wx + (size_t)(slc * 256 + bg) * 2048 + l * 2;
            #pragma unroll
            for (int i = 0; i < 4; ++i) {
                uint2 vv;
                vv.x = pack2(g[i][0], g[i][1]);
                vv.y = pack2(g[i][2], g[i][3]);
                *(uint2*)(dst + (w + 4 * i) * 128) = vv;
            }
        }
    }
}

// ============================================================================
// Recurrence block with FUSED value head (paired every 2 steps):
// 4 waves / 16 batch rows, 1 lgkm barrier/step, 2-deep wx prefetch.
// ============================================================================
__device__ __forceinline__ void rec_block(
    ushort_t* smem,
    const short8* __restrict__ whhimg, const uint_t* __restrict__ wx,
    ushort_t* __restrict__ hws, float* __restrict__ cws,
    const float* __restrict__ Wv, const float* __restrict__ bv,
    float* __restrict__ out, int rc0, int first, int last, int csr)
{
    const int t = threadIdx.x;
    const int w = t >> 6, l = t & 63, q = l >> 4, m = l & 15;
    const int bg = blockIdx.x, b0 = bg * NB;
    const int vr = t >> 4, vp = t & 15;           // value-head row / col-group

    short8 whhf[4][2];
    #pragma unroll
    for (int a = 0; a < 4; ++a)
        #pragma unroll
        for (int kk = 0; kk < 2; ++kk)
            whhf[a][kk] = whhimg[(((w + 4 * a) * 2) + kk) * 64 + l];

    const float4 wv = *(const float4*)(Wv + vp * 4);
    const float bvv = bv[0];

    float creg[4], hlast[4] = {0.f, 0.f, 0.f, 0.f};
    if (first) {
        #pragma unroll
        for (int r = 0; r < 4; ++r) creg[r] = 0.f;
        int idx4 = t * 4, row = idx4 >> 6, col = idx4 & 63;
        uint2 z; z.x = 0u; z.y = 0u;
        *(uint2*)&smem[row * SH_STR + col] = z;
    } else {
        int idx4 = t * 4, row = idx4 >> 6, col = idx4 & 63;
        uint2 hv2 = *(const uint2*)((const uint_t*)(hws + (size_t)bg * 1024 + idx4));
        *(uint2*)&smem[row * SH_STR + col] = hv2;
        float4 cv = *(const float4*)(cws + ((size_t)bg * 256 + t) * 4);
        creg[0] = cv.x; creg[1] = cv.y; creg[2] = cv.z; creg[3] = cv.w;
    }

    uint2 upf[2][4];
    {
        const uint_t* p0 = wx + (size_t)(0 * 256 + bg) * 2048 + l * 2;
        const uint_t* p1 = wx + (size_t)(1 * 256 + bg) * 2048 + l * 2;
        #pragma unroll
        for (int a = 0; a < 4; ++a) {
            upf[0][a] = *(const uint2*)(p0 + (w + 4 * a) * 128);
            upf[1][a] = *(const uint2*)(p1 + (w + 4 * a) * 128);
        }
    }

    barrier_lgkm();

    // core of one step (PAR = buffer parity, SLV = step index); no val head.
    #define REC_CORE(PAR, SLV)                                                          \
        const int sl_ = (SLV);                                                          \
        ushort_t* shc = smem + (PAR) * (NB * SH_STR);                                   \
        ushort_t* shn = smem + (1 - (PAR)) * (NB * SH_STR);                             \
        short8 af0 = *(const short8*)&shc[m * SH_STR + q * 8];                          \
        short8 af1 = *(const short8*)&shc[m * SH_STR + 32 + q * 8];                     \
        f32x4 g[4];                                                                     \
        _Pragma("unroll")                                                               \
        for (int a = 0; a < 4; ++a) {                                                   \
            g[a][0] = bflo(upf[PAR][a].x); g[a][1] = bfhi(upf[PAR][a].x);               \
            g[a][2] = bflo(upf[PAR][a].y); g[a][3] = bfhi(upf[PAR][a].y);               \
        }                                                                               \
        {                                                                               \
            int snext = (sl_ + 2 < csr) ? (sl_ + 2) : sl_;                              \
            const uint_t* pn = wx + (size_t)(snext * 256 + bg) * 2048 + l * 2;          \
            _Pragma("unroll")                                                           \
            for (int a = 0; a < 4; ++a)                                                 \
                upf[PAR][a] = *(const uint2*)(pn + (w + 4 * a) * 128);                  \
        }                                                                               \
        _Pragma("unroll")                                                               \
        for (int a = 0; a < 4; ++a) {                                                   \
            g[a] = __builtin_amdgcn_mfma_f32_16x16x32_bf16(af0, whhf[a][0], g[a], 0, 0, 0); \
            g[a] = __builtin_amdgcn_mfma_f32_16x16x32_bf16(af1, whhf[a][1], g[a], 0, 0, 0); \
        }                                                                               \
        _Pragma("unroll")                                                               \
        for (int r = 0; r < 4; ++r) {                                                   \
            float gi = fsig(g[0][r]);                                                   \
            float gf = fsig(g[1][r]);                                                   \
            float gg = ftanh(g[2][r]);                                                  \
            float go = fsig(g[3][r]);                                                   \
            float c  = gf * creg[r] + gi * gg;                                          \
            creg[r] = c;                                                                \
            float h = go * ftanh(c);                                                    \
            hlast[r] = h;                                                               \
            shn[(q * 4 + r) * SH_STR + 16 * w + m] = f2bf(h);                           \
        }

    for (int sl = 0; sl < csr; sl += 2) {
        {   // even step (PAR=0): compute only
            REC_CORE(0, sl);
            barrier_lgkm();
        }
        {   // odd step (PAR=1): compute + dual val head for steps sl, sl+1
            // early read of h(sl) from shc (stable until step sl+2's writes,
            // which happen after the next barrier)
            uint2 hvA = *(const uint2*)&smem[1 * (NB * SH_STR) + vr * SH_STR + vp * 4];
            REC_CORE(1, sl + 1);
            barrier_lgkm();
            uint2 hvB = *(const uint2*)&shn[vr * SH_STR + vp * 4];   // h(sl+1)
            float pvA = bflo(hvA.x) * wv.x + bfhi(hvA.x) * wv.y
                      + bflo(hvA.y) * wv.z + bfhi(hvA.y) * wv.w;
            float pvB = bflo(hvB.x) * wv.x + bfhi(hvB.x) * wv.y
                      + bflo(hvB.y) * wv.z + bfhi(hvB.y) * wv.w;
            pvA += __shfl_xor(pvA, 1, 16);  pvB += __shfl_xor(pvB, 1, 16);
            pvA += __shfl_xor(pvA, 2, 16);  pvB += __shfl_xor(pvB, 2, 16);
            pvA += __shfl_xor(pvA, 4, 16);  pvB += __shfl_xor(pvB, 4, 16);
            pvA += __shfl_xor(pvA, 8, 16);  pvB += __shfl_xor(pvB, 8, 16);
            if (vp == 0) {
                float2 o; o.x = pvA + bvv; o.y = pvB + bvv;
                *(float2*)&out[(size_t)(b0 + vr) * SS + rc0 + sl_ - 1] = o;
            }
        }
    }
    #undef REC_CORE

    if (!last) {
        const int jcol = 16 * w + m;
        #pragma unroll
        for (int r = 0; r < 4; ++r)
            hws[(size_t)bg * 1024 + (q * 4 + r) * 64 + jcol] = f2bf(hlast[r]);
        float4 cv; cv.x = creg[0]; cv.y = creg[1]; cv.z = creg[2]; cv.w = creg[3];
        *(float4*)(cws + ((size_t)bg * 256 + t) * 4) = cv;
    } else {
        const int jcol = 16 * w + m;
        #pragma unroll
        for (int r = 0; r < 4; ++r) {
            int row = b0 + q * 4 + r;
            out[BB * SS + (size_t)row * 64 + jcol]           = hlast[r];
            out[BB * SS + BB * 64 + (size_t)row * 64 + jcol] = creg[r];
        }
    }
}

// ============================================================================
// Combined pipeline dispatch: [0,nrec) rec(chunk i)+fused-val | rest enc(i+1).
// ============================================================================
__global__ __launch_bounds__(NT, 3)
void podcritic_step(const float* __restrict__ self_obs, const float* __restrict__ tm_obs,
                    const float* __restrict__ en_obs,   const float* __restrict__ cp_obs,
                    const float* __restrict__ b1, const float* __restrict__ b2,
                    const float* __restrict__ bih, const float* __restrict__ bhh,
                    const short8* __restrict__ img,
                    uint_t* __restrict__ wx_enc, const uint_t* __restrict__ wx_rec,
                    ushort_t* __restrict__ hws, float* __restrict__ cws,
                    const float* __restrict__ Wv, const float* __restrict__ bv,
                    float* __restrict__ out,
                    int enc_c0, int rec_c0, int nrec, int first, int last, int rec_cs)
{
    __shared__ __align__(16) ushort_t smem[ENC_LDS_USHORTS];
    const int bid = blockIdx.x;
    if (bid < nrec) {
        rec_block(smem, img + 160 * 64, wx_rec, hws, cws, Wv, bv, out,
                  rec_c0, first, last, rec_cs);
    } else {
        enc_block(smem, self_obs, tm_obs, en_obs, cp_obs, b1, b2, bih, bhh,
                  img, wx_enc, enc_c0, bid - nrec);
    }
}

// ============================================================================
// Fallback: fused kernel (only if ws too small) — round-2 structure.
// ============================================================================
__global__ __launch_bounds__(NT, 1)
void podcritic_mfma(const float* __restrict__ self_obs,
                    const float* __restrict__ tm_obs,
                    const float* __restrict__ en_obs,
                    const float* __restrict__ cp_obs,
                    const float* __restrict__ W1, const float* __restrict__ b1,
                    const float* __restrict__ W2, const float* __restrict__ b2,
                    const float* __restrict__ Wih, const float* __restrict__ bih,
                    const float* __restrict__ Whh, const float* __restrict__ bhh,
                    const float* __restrict__ Wv, const float* __restrict__ bv,
                    float* __restrict__ out)
{
    __shared__ __align__(16) ushort_t sx[2][NB * SX_STR];
    __shared__ __align__(16) ushort_t sh1[NB * SH1_STR];
    __shared__ __align__(16) ushort_t semb[NB * SEMB_STR];
    __shared__ __align__(16) ushort_t sh[NB * SH_STR];
    __shared__ float sWv[64];

    const int t  = threadIdx.x;
    const int w  = t >> 6;
    const int l  = t & 63;
    const int q  = l >> 4;
    const int m  = l & 15;
    const int b0 = blockIdx.x * NB;

    short8 w1f[4][2];
    short8 w2f[2][8];
    short8 wihf[4][4];
    short8 whhf[4][2];
    float bias1[4], bias2[2], bg[4];

    #pragma unroll
    for (int i = 0; i < 4; ++i) {
        int n = w * 64 + i * 16 + m;
        bias1[i] = b1[n];
        #pragma unroll
        for (int kk = 0; kk < 2; ++kk) {
            FragU u;
            #pragma unroll
            for (int j = 0; j < 8; ++j) {
                int k = kk * 32 + q * 8 + j;
                u.u[j] = f2bf(k < 47 ? W1[k * 256 + n] : 0.f);
            }
            w1f[i][kk] = u.v;
        }
    }
    #pragma unroll
    for (int i = 0; i < 2; ++i) {
        int n = 32 * w + i * 16 + m;
        bias2[i] = b2[n];
        #pragma unroll
        for (int kk = 0; kk < 8; ++kk) {
            FragU u;
            #pragma unroll
            for (int j = 0; j < 8; ++j) {
                int k = kk * 32 + q * 8 + j;
                u.u[j] = f2bf(W2[k * 128 + n]);
            }
            w2f[i][kk] = u.v;
        }
    }
    #pragma unroll
    for (int i = 0; i < 4; ++i) {
        int n = (w + 4 * i) * 16 + m;
        bg[i] = bih[n] + bhh[n];
        #pragma unroll
        for (int kk = 0; kk < 4; ++kk) {
            FragU u;
            #pragma unroll
            for (int j = 0; j < 8; ++j) {
                int k = kk * 32 + q * 8 + j;
                u.u[j] = f2bf(Wih[k * 256 + n]);
            }
            wihf[i][kk] = u.v;
        }
        #pragma unroll
        for (int kk = 0; kk < 2; ++kk) {
            FragU u;
            #pragma unroll
            for (int j = 0; j < 8; ++j) {
                int k = kk * 32 + q * 8 + j;
                u.u[j] = f2bf(Whh[k * 256 + n]);
            }
            whhf[i][kk] = u.v;
        }
    }
    const float bvv = bv[0];
    if (t < 64) sWv[t] = Wv[t];

    for (int idx = t; idx < NB * SH_STR; idx += NT) sh[idx] = 0;

    const int pcol = t & 63;
    const int prow = t >> 6;
    #pragma unroll
    for (int j = 0; j < 4; ++j) {
        int r  = 4 * j + prow;
        int bs = (b0 + r) * SS + 0;
        float v = 0.f;
        if (pcol < 15)      v = self_obs[bs * 15 + pcol];
        else if (pcol < 28) v = tm_obs[bs * 13 + (pcol - 15)];
        else if (pcol < 41) { int kk = pcol - 28;
                              v = 0.5f * (en_obs[(bs * 2) * 13 + kk] + en_obs[(bs * 2) * 13 + 13 + kk]); }
        else if (pcol < 47) v = cp_obs[bs * 6 + (pcol - 41)];
        sx[0][r * SX_STR + pcol] = f2bf(v);
    }
    __syncthreads();

    float creg[4] = {0.f, 0.f, 0.f, 0.f};
    float hreg[4] = {0.f, 0.f, 0.f, 0.f};
    int cur = 0;

    for (int s = 0; s < SS; ++s) {
        float pf[4];
        #pragma unroll
        for (int j = 0; j < 4; ++j) {
            float v = 0.f;
            if (s + 1 < SS) {
                int r  = 4 * j + prow;
                int bs = (b0 + r) * SS + (s + 1);
                if (pcol < 15)      v = self_obs[bs * 15 + pcol];
                else if (pcol < 28) v = tm_obs[bs * 13 + (pcol - 15)];
                else if (pcol < 41) { int kk = pcol - 28;
                                      v = 0.5f * (en_obs[(bs * 2) * 13 + kk] + en_obs[(bs * 2) * 13 + 13 + kk]); }
                else if (pcol < 47) v = cp_obs[bs * 6 + (pcol - 41)];
            }
            pf[j] = v;
        }

        {
            f32x4 c1[4] = {{0,0,0,0},{0,0,0,0},{0,0,0,0},{0,0,0,0}};
            #pragma unroll
            for (int kk = 0; kk < 2; ++kk) {
                short8 a = *(const short8*)&sx[cur][m * SX_STR + kk * 32 + q * 8];
                #pragma unroll
                for (int i = 0; i < 4; ++i)
                    c1[i] = __builtin_amdgcn_mfma_f32_16x16x32_bf16(a, w1f[i][kk], c1[i], 0, 0, 0);
            }
            #pragma unroll
            for (int i = 0; i < 4; ++i) {
                int col = w * 64 + i * 16 + m;
                #pragma unroll
                for (int r = 0; r < 4; ++r)
                    sh1[(q * 4 + r) * SH1_STR + col] = f2bf(fmaxf(c1[i][r] + bias1[i], 0.f));
            }
        }
        __syncthreads();

        {
            f32x4 c2[2] = {{0,0,0,0},{0,0,0,0}};
            #pragma unroll
            for (int kk = 0; kk < 8; ++kk) {
                short8 a = *(const short8*)&sh1[m * SH1_STR + kk * 32 + q * 8];
                #pragma unroll
                for (int i = 0; i < 2; ++i)
                    c2[i] = __builtin_amdgcn_mfma_f32_16x16x32_bf16(a, w2f[i][kk], c2[i], 0, 0, 0);
            }
            #pragma unroll
            for (int i = 0; i < 2; ++i) {
                int col = 32 * w + i * 16 + m;
                #pragma unroll
                for (int r = 0; r < 4; ++r)
                    semb[(q * 4 + r) * SEMB_STR + col] = f2bf(fmaxf(c2[i][r] + bias2[i], 0.f));
            }
        }
        __syncthreads();

        {
            f32x4 g[4];
            #pragma unroll
            for (int i = 0; i < 4; ++i) g[i] = (f32x4){bg[i], bg[i], bg[i], bg[i]};
            #pragma unroll
            for (int kk = 0; kk < 4; ++kk) {
                short8 a = *(const short8*)&semb[m * SEMB_STR + kk * 32 + q * 8];
                #pragma unroll
                for (int i = 0; i < 4; ++i)
                    g[i] = __builtin_amdgcn_mfma_f32_16x16x32_bf16(a, wihf[i][kk], g[i], 0, 0, 0);
            }
            #pragma unroll
            for (int kk = 0; kk < 2; ++kk) {
                short8 a = *(const short8*)&sh[m * SH_STR + kk * 32 + q * 8];
                #pragma unroll
                for (int i = 0; i < 4; ++i)
                    g[i] = __builtin_amdgcn_mfma_f32_16x16x32_bf16(a, whhf[i][kk], g[i], 0, 0, 0);
            }
            const int jcol = 16 * w + m;
            #pragma unroll
            for (int r = 0; r < 4; ++r) {
                float gi = fsig(g[0][r]);
                float gf = fsig(g[1][r]);
                float gg = ftanh(g[2][r]);
                float go = fsig(g[3][r]);
                float c  = gf * creg[r] + gi * gg;
                creg[r] = c;
                float h = go * ftanh(c);
                hreg[r] = h;
                sh[(q * 4 + r) * SH_STR + jcol] = f2bf(h);
            }
            #pragma unroll
            for (int j = 0; j < 4; ++j) {
                int r = 4 * j + prow;
                sx[cur ^ 1][r * SX_STR + pcol] = f2bf(pf[j]);
            }
        }
        __syncthreads();

        {
            int r = t >> 4, pp = t & 15;
            const ushort_t* hp = &sh[r * SH_STR + pp * 4];
            float pv = 0.f;
            #pragma unroll
            for (int j = 0; j < 4; ++j) pv += bf2f(hp[j]) * sWv[pp * 4 + j];
            pv += __shfl_xor(pv, 1, 16);
            pv += __shfl_xor(pv, 2, 16);
            pv += __shfl_xor(pv, 4, 16);
            pv += __shfl_xor(pv, 8, 16);
            if (pp == 0) out[(b0 + r) * SS + s] = pv + bvv;
        }
        cur ^= 1;
    }

    {
        const int jcol = 16 * w + m;
        #pragma unroll
        for (int r = 0; r < 4; ++r) {
            int row = b0 + q * 4 + r;
            out[BB * SS + row * 64 + jcol]           = hreg[r];
            out[BB * SS + BB * 64 + row * 64 + jcol] = creg[r];
        }
    }
}

extern "C" void kernel_launch(void* const* d_in, const int* in_sizes, int n_in,
                              void* d_out, int out_size, void* d_ws, size_t ws_size,
                              hipStream_t stream) {
    const float* self_obs = (const float*)d_in[0];
    const float* tm_obs   = (const float*)d_in[1];
    const float* en_obs   = (const float*)d_in[2];
    const float* cp_obs   = (const float*)d_in[3];
    const float* W1  = (const float*)d_in[4];
    const float* b1  = (const float*)d_in[5];
    const float* W2  = (const float*)d_in[6];
    const float* b2  = (const float*)d_in[7];
    const float* Wih = (const float*)d_in[8];
    const float* bih = (const float*)d_in[9];
    const float* Whh = (const float*)d_in[10];
    const float* bhh = (const float*)d_in[11];
    const float* Wv  = (const float*)d_in[12];
    const float* bv  = (const float*)d_in[13];
    float* out = (float*)d_out;

    const size_t h_bytes   = 256 * 1024 * 2;                // 524,288
    const size_t c_bytes   = 256 * 1024 * 4;                // 1,048,576
    const size_t img_bytes = 192 * 64 * 16;                 // 196,608

    auto need_for = [&](int cs) -> size_t {
        size_t wx_chunk = (size_t)cs * 256 * 2048 * 4;
        return 2 * wx_chunk + h_bytes + c_bytes + img_bytes;
    };

    // variable chunk schedule (all chunks divisible by 4 for M=64 enc):
    // small head kills the pipeline bubble, small tail kills the rec drain.
    int chunks[10]; int nch = 0; int csmax = 0;
    if (ws_size >= need_for(32)) {
        csmax = 32; nch = 6;
        chunks[0] = 4; chunks[1] = 28; chunks[2] = 32;
        chunks[3] = 32; chunks[4] = 28; chunks[5] = 4;
    } else if (ws_size >= need_for(16)) {
        csmax = 16; nch = 10;
        chunks[0] = 4; chunks[1] = 12;
        for (int i = 2; i < 8; ++i) chunks[i] = 16;
        chunks[8] = 12; chunks[9] = 4;
    }

    if (csmax) {
        const size_t wx_chunk = (size_t)csmax * 256 * 2048 * 4;
        char* p = (char*)d_ws;
        uint_t*   wxb[2] = { (uint_t*)p, (uint_t*)(p + wx_chunk) };
        ushort_t* hws    = (ushort_t*)(p + 2 * wx_chunk);
        float*    cws    = (float*)(p + 2 * wx_chunk + h_bytes);
        short8*   img    = (short8*)(p + 2 * wx_chunk + h_bytes + c_bytes);

        int off[11]; off[0] = 0;
        for (int i = 0; i < nch; ++i) off[i + 1] = off[i] + chunks[i];

        podcritic_prep<<<48, NT, 0, stream>>>(W1, W2, Wih, Whh, img);

        // head: enc chunk 0 alone (small -> tiny bubble); M=64 -> 64 blk/step
        podcritic_step<<<64 * chunks[0], NT, 0, stream>>>(
            self_obs, tm_obs, en_obs, cp_obs, b1, b2, bih, bhh, img,
            wxb[0], wxb[0], hws, cws, Wv, bv, out,
            /*enc_c0=*/0, /*rec_c0=*/0, /*nrec=*/0, 0, 0, chunks[0]);

        for (int i = 0; i < nch; ++i) {
            int nenc = (i + 1 < nch) ? 64 * chunks[i + 1] : 0;
            int grid = 256 + nenc;
            podcritic_step<<<grid, NT, 0, stream>>>(
                self_obs, tm_obs, en_obs, cp_obs, b1, b2, bih, bhh, img,
                wxb[(i + 1) & 1], wxb[i & 1], hws, cws, Wv, bv, out,
                /*enc_c0=*/off[i + 1], /*rec_c0=*/off[i],
                /*nrec=*/256, (i == 0) ? 1 : 0, (i == nch - 1) ? 1 : 0, chunks[i]);
        }
    } else {
        podcritic_mfma<<<BB / NB, NT, 0, stream>>>(
            self_obs, tm_obs, en_obs, cp_obs,
            W1, b1, W2, b2, Wih, bih, Whh, bhh, Wv, bv, out);
    }
}